// Round 9
// baseline (102.444 us; speedup 1.0000x reference)
//
#include <hip/hip_runtime.h>

#define F 2048
#define BATCH 1024

typedef short bf16x8 __attribute__((ext_vector_type(8)));
typedef float f32x4 __attribute__((ext_vector_type(4)));
typedef unsigned short u16x4 __attribute__((ext_vector_type(4)));

// round-to-nearest-even f32 -> bf16 (bit trick, finite values only)
__device__ __forceinline__ unsigned short f2bf(float f) {
  unsigned u = __builtin_bit_cast(unsigned, f);
  unsigned r = (u + 0x7fffu + ((u >> 16) & 1u)) >> 16;
  return (unsigned short)r;
}

__device__ __forceinline__ void gload_lds16(const void* g, void* l) {
  __builtin_amdgcn_global_load_lds(
      (const __attribute__((address_space(1))) unsigned int*)g,
      (__attribute__((address_space(3))) unsigned int*)l,
      16, 0, 0);
}

// ---------------------------------------------------------------------------
// K1: fused prep+convert (≈4-7 us, BW-bound).
// blocks [0,1024): convert inputs f32 -> bf16, 2048 elems/block.
// blocks [1024,1536): prep, one wave per weight row:
//   w = exp(weight) in diag 32-block, weight below, 0 above
//   w_n = exp(dw)*w/||w|| bf16, zero-padded out to the row's 128-col
//   boundary (wzero) so both 64-wide and 128-wide gemm tiles stage only
//   written bytes. exp_blocks[r,p] = exp(dw + weight[r,d0+p] - 0.5*log(wsn))
// ---------------------------------------------------------------------------
__global__ __launch_bounds__(256) void prep_convert_kernel(
    const float* __restrict__ inputs, unsigned short* __restrict__ a_bf,
    const float* __restrict__ weight, const float* __restrict__ dw,
    unsigned short* __restrict__ w_n, float* __restrict__ exp_blocks)
{
  int bid = blockIdx.x;
  if (bid < 1024) {
    int idx = bid * 2048 + threadIdx.x * 8;
    float4 v0 = *(const float4*)(inputs + idx);
    float4 v1 = *(const float4*)(inputs + idx + 4);
    union { unsigned short s[8]; bf16x8 v; } o;
    o.s[0] = f2bf(v0.x); o.s[1] = f2bf(v0.y); o.s[2] = f2bf(v0.z); o.s[3] = f2bf(v0.w);
    o.s[4] = f2bf(v1.x); o.s[5] = f2bf(v1.y); o.s[6] = f2bf(v1.z); o.s[7] = f2bf(v1.w);
    *(bf16x8*)(a_bf + idx) = o.v;
    return;
  }
  int rb = bid - 1024;
  int lane = threadIdx.x & 63;
  int r = rb * 4 + (threadIdx.x >> 6);
  int i = r >> 5;
  int lim = (i + 1) * 32;             // valid-data end (mult of 32)
  int wzero = (r & ~127) + 128;       // zero-pad end (covers 64- and 128-tiles)
  int d0 = i * 32;
  const float* wrow = weight + (size_t)r * F;

  float ss = 0.f;
  for (int j = lane; j < lim / 4; j += 64) {
    float4 v = ((const float4*)wrow)[j];
    if (j * 4 >= d0) {
      v.x = __expf(v.x); v.y = __expf(v.y); v.z = __expf(v.z); v.w = __expf(v.w);
    }
    ss += v.x * v.x + v.y * v.y + v.z * v.z + v.w * v.w;
  }
#pragma unroll
  for (int d = 32; d > 0; d >>= 1) ss += __shfl_xor(ss, d, 64);

  float dwr = dw[r];
  float scale = __expf(dwr) * rsqrtf(ss);
  float halflog = 0.5f * __logf(ss);

  unsigned short* onrow = w_n + (size_t)r * F;
  for (int j = lane; j < wzero / 4; j += 64) {
    u16x4 o = {0, 0, 0, 0};
    if (j * 4 < lim) {
      float4 v = ((const float4*)wrow)[j];
      if (j * 4 >= d0) {
        v.x = __expf(v.x); v.y = __expf(v.y); v.z = __expf(v.z); v.w = __expf(v.w);
      }
      o[0] = f2bf(scale * v.x); o[1] = f2bf(scale * v.y);
      o[2] = f2bf(scale * v.z); o[3] = f2bf(scale * v.w);
    }
    *(u16x4*)(onrow + j * 4) = o;
  }
  if (lane < 32) {
    exp_blocks[(size_t)r * 32 + lane] = __expf(dwr + wrow[d0 + lane] - halflog);
  }
}

// ---------------------------------------------------------------------------
// K2: hybrid-tile gemm + MFMA logdet, 528 blocks, 64 KB LDS -> 2 blocks/CU.
// ids [0,80): gemm 128x128 (tn128 = 9-(id>>3) heavy-first, tm = id&7).
//   BK=64, 4 waves x (64x64, 4x4 frags), 2-stage LDS double buffer (2x32KB),
//   counted vmcnt(8) (8 gload_lds/wave/stage), raw s_barrier, XOR swizzle.
//   Halves LDS bytes/MAC vs 64^2 and 4x the MFMA per barrier window.
// ids [80,272): gemm 64x64 (col = 31-((id-80)>>4) in 20..31, tm = (id-80)&15).
//   Verified R8 structure: 3-stage pipeline, vmcnt(8/4/0), nkt = col+1.
//   Heavy columns stay 64-wide to cap the critical path (~32x384 cyc).
// ids [272,528): logdet via MFMA, LDS-free (verified R7/R8):
//   ld[b,i,o] = log( sum_q eb[i,o,q] * exp(grad[b,i,q]) )
// ---------------------------------------------------------------------------
__global__ __launch_bounds__(256, 2) void gemm_logdet_kernel(
    const unsigned short* __restrict__ A, const unsigned short* __restrict__ W,
    const float* __restrict__ bias, const float* __restrict__ grad,
    const float* __restrict__ exp_blocks, float* __restrict__ out,
    float* __restrict__ ld)
{
  __shared__ __align__(16) char smem[65536];  // 64 KiB -> 2 blocks/CU

  int id = blockIdx.x;
  int tid = threadIdx.x;
  int lane = tid & 63, wid = tid >> 6;
  int l15 = lane & 15, lg = lane >> 4;

  if (id < 80) {
    // ================= gemm 128x128 =================
    int tn = 9 - (id >> 3);          // 9..0, heaviest first
    int tm = id & 7;
    int m0 = tm * 128, n0 = tn * 128;
    int nkt = 2 * (tn + 1);          // BK=64 steps; K-limit = 128*(tn+1)

    int wm = wid >> 1, wn = wid & 1; // wave quadrant (64x64)
    int srow = lane >> 3;            // 8 rows per staging instr
    int schunk = (lane & 7) ^ (srow & 7);

    auto stage = [&](int kt) {
      size_t kb = (size_t)kt * 128;  // byte offset in K (BK=64 bf16)
      char* base = smem + (kt & 1) * 32768;
#pragma unroll
      for (int e = 0; e < 4; ++e) {
        int sg = wid * 4 + e;        // 16 groups of 8 rows
        int row = sg * 8 + srow;
        gload_lds16((const char*)A + (size_t)(m0 + row) * 4096 + kb + schunk * 16,
                    base + sg * 1024);
        gload_lds16((const char*)W + (size_t)(n0 + row) * 4096 + kb + schunk * 16,
                    base + 16384 + sg * 1024);
      }
    };

    f32x4 acc[4][4] = {};

    auto compute = [&](int kt) {
      const char* sA = smem + (kt & 1) * 32768;
      const char* sB = sA + 16384;
      bf16x8 af[4][2], bfr[4][2];
#pragma unroll
      for (int mi = 0; mi < 4; ++mi) {
        int row = wm * 64 + mi * 16 + l15;
#pragma unroll
        for (int ks = 0; ks < 2; ++ks) {
          int ch = (ks * 4 + lg) ^ (row & 7);
          af[mi][ks] = *(const bf16x8*)(sA + row * 128 + ch * 16);
        }
      }
#pragma unroll
      for (int ni = 0; ni < 4; ++ni) {
        int row = wn * 64 + ni * 16 + l15;
#pragma unroll
        for (int ks = 0; ks < 2; ++ks) {
          int ch = (ks * 4 + lg) ^ (row & 7);
          bfr[ni][ks] = *(const bf16x8*)(sB + row * 128 + ch * 16);
        }
      }
#pragma unroll
      for (int ks = 0; ks < 2; ++ks)
#pragma unroll
        for (int mi = 0; mi < 4; ++mi)
#pragma unroll
          for (int ni = 0; ni < 4; ++ni)
            acc[mi][ni] = __builtin_amdgcn_mfma_f32_16x16x32_bf16(
                af[mi][ks], bfr[ni][ks], acc[mi][ni], 0, 0, 0);
    };

    stage(0);
    for (int kt = 0; kt < nkt; ++kt) {
      if (kt + 1 < nkt) {
        stage(kt + 1);
        asm volatile("s_waitcnt vmcnt(8)" ::: "memory");   // stage kt landed
      } else {
        asm volatile("s_waitcnt vmcnt(0)" ::: "memory");
      }
      __builtin_amdgcn_s_barrier();
      compute(kt);
      __builtin_amdgcn_s_barrier();  // reads done before buf reuse
    }

#pragma unroll
    for (int ni = 0; ni < 4; ++ni) {
      float bv = bias[n0 + wn * 64 + ni * 16 + l15];
#pragma unroll
      for (int mi = 0; mi < 4; ++mi)
#pragma unroll
        for (int j = 0; j < 4; ++j) {
          int m = m0 + wm * 64 + mi * 16 + lg * 4 + j;   // C/D: row=(lane>>4)*4+reg
          int n = n0 + wn * 64 + ni * 16 + l15;          //      col=lane&15
          out[(size_t)m * F + n] = acc[mi][ni][j] + bv;
        }
    }
  } else if (id < 272) {
    // ================= gemm 64x64 (heavy cols 20..31) =================
    int lid = id - 80;
    int tn = 31 - (lid >> 4);        // 31..20, heaviest first within group
    int tm = lid & 15;
    int m0 = tm * 64, n0 = tn * 64;
    int nkt = tn + 1;

    int wm = wid >> 1, wn = wid & 1;
    int srow = lane >> 3;
    int schunk = (lane & 7) ^ (srow & 7);

    auto stage = [&](int kt) {
      size_t kb = (size_t)kt * 128;  // BK=64 bf16
      char* base = smem + (kt % 3) * 16384;
#pragma unroll
      for (int e = 0; e < 2; ++e) {
        int sg = wid * 2 + e;        // 8 groups of 8 rows
        int row = sg * 8 + srow;
        gload_lds16((const char*)A + (size_t)(m0 + row) * 4096 + kb + schunk * 16,
                    base + sg * 1024);
        gload_lds16((const char*)W + (size_t)(n0 + row) * 4096 + kb + schunk * 16,
                    base + 8192 + sg * 1024);
      }
    };

    f32x4 acc[2][2] = {};

    auto compute = [&](int kt) {
      const char* sA = smem + (kt % 3) * 16384;
      const char* sB = sA + 8192;
      bf16x8 af[2][2], bfr[2][2];
#pragma unroll
      for (int mi = 0; mi < 2; ++mi) {
        int row = wm * 32 + mi * 16 + l15;
#pragma unroll
        for (int ks = 0; ks < 2; ++ks) {
          int ch = (ks * 4 + lg) ^ (row & 7);
          af[mi][ks] = *(const bf16x8*)(sA + row * 128 + ch * 16);
        }
      }
#pragma unroll
      for (int ni = 0; ni < 2; ++ni) {
        int row = wn * 32 + ni * 16 + l15;
#pragma unroll
        for (int ks = 0; ks < 2; ++ks) {
          int ch = (ks * 4 + lg) ^ (row & 7);
          bfr[ni][ks] = *(const bf16x8*)(sB + row * 128 + ch * 16);
        }
      }
#pragma unroll
      for (int ks = 0; ks < 2; ++ks)
#pragma unroll
        for (int mi = 0; mi < 2; ++mi)
#pragma unroll
          for (int ni = 0; ni < 2; ++ni)
            acc[mi][ni] = __builtin_amdgcn_mfma_f32_16x16x32_bf16(
                af[mi][ks], bfr[ni][ks], acc[mi][ni], 0, 0, 0);
    };

    stage(0);
    if (nkt > 1) stage(1);
    for (int kt = 0; kt < nkt; ++kt) {
      if (kt + 2 < nkt) stage(kt + 2);
      int rem = nkt - 1 - kt;
      if (rem >= 2)      asm volatile("s_waitcnt vmcnt(8)" ::: "memory");
      else if (rem == 1) asm volatile("s_waitcnt vmcnt(4)" ::: "memory");
      else               asm volatile("s_waitcnt vmcnt(0)" ::: "memory");
      __builtin_amdgcn_s_barrier();
      compute(kt);
      __builtin_amdgcn_s_barrier();
    }

    float bv0 = bias[n0 + wn * 32 + l15];
    float bv1 = bias[n0 + wn * 32 + 16 + l15];
#pragma unroll
    for (int mi = 0; mi < 2; ++mi)
#pragma unroll
      for (int ni = 0; ni < 2; ++ni) {
        float bv = ni ? bv1 : bv0;
#pragma unroll
        for (int j = 0; j < 4; ++j) {
          int m = m0 + wm * 32 + mi * 16 + lg * 4 + j;
          int n = n0 + wn * 32 + ni * 16 + l15;
          out[(size_t)m * F + n] = acc[mi][ni][j] + bv;
        }
      }
  } else {
    // ================= logdet (MFMA, LDS-free) =================
    int lid = id - 272;                // 0..255
    int i = lid & 63;
    int bq = lid >> 6;                 // batch quarter
    int b_base = bq * 256 + wid * 64;  // this wave: 64 batches

    const float* ebp = exp_blocks + (size_t)i * 1024;
    bf16x8 eb_lo, eb_hi;
    {
      float4 a0 = *(const float4*)(ebp + l15 * 32 + lg * 8);
      float4 a1 = *(const float4*)(ebp + l15 * 32 + lg * 8 + 4);
      float4 b0 = *(const float4*)(ebp + (16 + l15) * 32 + lg * 8);
      float4 b1 = *(const float4*)(ebp + (16 + l15) * 32 + lg * 8 + 4);
      union { unsigned short s[8]; bf16x8 v; } plo, phi;
      plo.s[0] = f2bf(a0.x); plo.s[1] = f2bf(a0.y); plo.s[2] = f2bf(a0.z); plo.s[3] = f2bf(a0.w);
      plo.s[4] = f2bf(a1.x); plo.s[5] = f2bf(a1.y); plo.s[6] = f2bf(a1.z); plo.s[7] = f2bf(a1.w);
      phi.s[0] = f2bf(b0.x); phi.s[1] = f2bf(b0.y); phi.s[2] = f2bf(b0.z); phi.s[3] = f2bf(b0.w);
      phi.s[4] = f2bf(b1.x); phi.s[5] = f2bf(b1.y); phi.s[6] = f2bf(b1.z); phi.s[7] = f2bf(b1.w);
      eb_lo = plo.v; eb_hi = phi.v;
    }

    const f32x4 zero = {0.f, 0.f, 0.f, 0.f};
#pragma unroll
    for (int g = 0; g < 4; ++g) {
      int brow = b_base + g * 16 + l15;
      const float* gp = grad + (size_t)brow * 2048 + i * 32 + lg * 8;
      float4 g0 = *(const float4*)gp;
      float4 g1 = *(const float4*)(gp + 4);
      union { unsigned short s[8]; bf16x8 v; } pg;
      pg.s[0] = f2bf(__expf(g0.x)); pg.s[1] = f2bf(__expf(g0.y));
      pg.s[2] = f2bf(__expf(g0.z)); pg.s[3] = f2bf(__expf(g0.w));
      pg.s[4] = f2bf(__expf(g1.x)); pg.s[5] = f2bf(__expf(g1.y));
      pg.s[6] = f2bf(__expf(g1.z)); pg.s[7] = f2bf(__expf(g1.w));

      f32x4 dlo = __builtin_amdgcn_mfma_f32_16x16x32_bf16(pg.v, eb_lo, zero, 0, 0, 0);
      f32x4 dhi = __builtin_amdgcn_mfma_f32_16x16x32_bf16(pg.v, eb_hi, zero, 0, 0, 0);

#pragma unroll
      for (int j = 0; j < 4; ++j) {
        int bb = b_base + g * 16 + lg * 4 + j;   // D row = (lane>>4)*4 + reg
        float* dst = ld + ((size_t)bb * 64 + i) * 32;
        dst[l15] = __logf(dlo[j]);               // D col = lane&15
        dst[16 + l15] = __logf(dhi[j]);
      }
    }
  }
}

// ---------------------------------------------------------------------------
extern "C" void kernel_launch(void* const* d_in, const int* in_sizes, int n_in,
                              void* d_out, int out_size, void* d_ws, size_t ws_size,
                              hipStream_t stream)
{
  const float* inputs = (const float*)d_in[0];
  const float* grad   = (const float*)d_in[1];
  const float* weight = (const float*)d_in[2];
  const float* dw     = (const float*)d_in[3];
  const float* bias   = (const float*)d_in[4];

  float* out = (float*)d_out;                  // 1024*2048
  float* ld  = out + (size_t)BATCH * F;        // 1024*64*32

  unsigned short* w_n  = (unsigned short*)d_ws;              // 8 MiB
  unsigned short* a_bf = w_n + (size_t)F * F;                // 4 MiB
  float* exp_blocks    = (float*)(a_bf + (size_t)BATCH * F); // 256 KiB

  prep_convert_kernel<<<1536, 256, 0, stream>>>(inputs, a_bf, weight, dw, w_n, exp_blocks);
  gemm_logdet_kernel<<<528, 256, 0, stream>>>(a_bf, w_n, bias, grad, exp_blocks, out, ld);
}